// Round 6
// baseline (206.799 us; speedup 1.0000x reference)
//
#include <hip/hip_runtime.h>
#include <math.h>

#define VOX 262144  // 64^3

__device__ __forceinline__ int clampi(int v, int lo, int hi) {
    return v < lo ? lo : (v > hi ? hi : v);
}

__device__ __forceinline__ float fast_tanh(float x) {
    float e = __expf(2.f * x);
    return 1.f - 2.f / (e + 1.f);
}

// ---- merged setup: feat transpose (blocks 0..8191), stats zero (8192),
//      weight transpose (8193..8208) ----
__global__ void k_setup(const float* __restrict__ f, float* __restrict__ ft,
                        float* __restrict__ stats, const float* __restrict__ w,
                        float* __restrict__ wT) {
    int bid = blockIdx.x;
    if (bid < 8192) {
        int idx = bid * 256 + threadIdx.x;  // (ci,z,y,x), coalesced reads
        int x = idx & 63, y = (idx >> 6) & 63, z = (idx >> 12) & 63, ci = idx >> 18;
        ft[(((z * 64 + y) * 64 + x) << 3) + ci] = f[idx];
    } else if (bid == 8192) {
        if (threadIdx.x < 64) stats[threadIdx.x] = 0.f;
    } else {
        int i = (bid - 8193) * 256 + threadIdx.x;  // over 18*8*27 = 3888
        if (i < 3888) {
            int c = i / 216, r = i % 216;
            int ci = r / 27, k = r % 27;
            wT[(k * 8 + ci) * 18 + c] = w[i];  // wT[k][ci][18]
        }
    }
}

// ---- offset conv (3x3x3, 8->18ch) + BN stats; LDS-staged input tile ----
// Block = 2x2 (d,wy) tile x 64 x = 256 outputs, 1 voxel/thread, 18 ch/thread.
// Stage 4x4 rows x 64 x x 8 ci = 32 KB LDS once; serve all 216 taps/thread
// from LDS (stride-1 = conflict-free). Weights scalar via s_load.
// XCD d-slab swizzle: slab s -> d in [8s, 8s+8).
__global__ __launch_bounds__(256, 5) void k_conv_off(
        const float* __restrict__ f, const float* __restrict__ wT,
        const float* __restrict__ b, float* __restrict__ offs,
        float* __restrict__ stats) {
    __shared__ float tile[8192];  // [ci][dr][wr][x] = ((ci*4+dr)*4+wr)*64+x

    int slab = blockIdx.x & 7, inner = blockIdx.x >> 3;   // 8 slabs x 128
    int dt = slab * 4 + (inner >> 5);                     // d-tile 0..31
    int wt = inner & 31;                                  // wy-tile 0..31

    int x = threadIdx.x & 63;
    int sub = threadIdx.x >> 6;          // 0..3
    int od_l = sub >> 1, ow_l = sub & 1; // local output (d,wy)
    int od = dt * 2 + od_l, ow = wt * 2 + ow_l;
    int lane = x;

    // ---- stage input tile (rows: ci 8 x dr 4 x wr 4), zeros at boundaries ----
#pragma unroll 8
    for (int it = 0; it < 32; it++) {
        int r = it * 4 + sub;            // row 0..127, one row per wave
        int ci = r >> 4, dr = (r >> 2) & 3, wr = r & 3;
        int dd = dt * 2 - 1 + dr;
        int ww = wt * 2 - 1 + wr;
        bool ok = ((unsigned)dd < 64u) & ((unsigned)ww < 64u);  // wave-uniform
        float v = 0.f;
        if (ok) v = f[((ci * 64 + dd) * 64 + ww) * 64 + x];
        tile[r * 64 + x] = v;
    }
    __syncthreads();

    int x0 = x > 0 ? x - 1 : 0;
    int x2 = x < 63 ? x + 1 : 63;
    float mh0 = x > 0 ? 1.f : 0.f;
    float mh2 = x < 63 ? 1.f : 0.f;

    float acc[18];
#pragma unroll
    for (int c = 0; c < 18; c++) acc[c] = b[c];

#pragma unroll
    for (int p = 0; p < 9; p++) {        // (kd,kw) pairs
        int kd = p / 3, kw = p % 3;
        int dr = od_l + kd, wr = ow_l + kw;
        int rbase = (dr * 4 + wr) * 64;  // + ci*1024
#pragma unroll
        for (int ci = 0; ci < 8; ci++) {
            int base = ci * 1024 + rbase;
            float v0 = tile[base + x0] * mh0;
            float v1 = tile[base + x];
            float v2 = tile[base + x2] * mh2;
            const float* wp = wT + (p * 3) * 144 + ci * 18;  // kh stride 144
#pragma unroll
            for (int c = 0; c < 18; c++) {
                float a = acc[c];
                a = fmaf(v0, wp[c], a);
                a = fmaf(v1, wp[144 + c], a);
                a = fmaf(v2, wp[288 + c], a);
                acc[c] = a;
            }
        }
    }

    int vox = (od * 64 + ow) * 64 + x;
#pragma unroll
    for (int c = 0; c < 18; c++) offs[c * VOX + vox] = acc[c];

    // ---- BN stats: reuse tile[0..35] after all LDS reads are done ----
    __syncthreads();
    if (threadIdx.x < 36) tile[threadIdx.x] = 0.f;
    __syncthreads();
#pragma unroll
    for (int c = 0; c < 18; c++) {
        float s = acc[c], q = acc[c] * acc[c];
#pragma unroll
        for (int o = 32; o > 0; o >>= 1) {
            s += __shfl_xor(s, o);
            q += __shfl_xor(q, o);
        }
        if (lane == 0) {
            atomicAdd(&tile[c], s);
            atomicAdd(&tile[18 + c], q);
        }
    }
    __syncthreads();
    if (threadIdx.x < 36) atomicAdd(&stats[threadIdx.x], tile[threadIdx.x]);
}

// ---- main: BN+tanh+cumsum + bilinear(z,y) gather + (1,1,9) conv + GN stats.
//      R2 structure (per-tap branch) + XCD z-slab swizzle for L2 locality. ----
__global__ __launch_bounds__(256) void k_main(
        const float* __restrict__ ft, const float* __restrict__ offs,
        const float* __restrict__ stats, const float* __restrict__ bn_g,
        const float* __restrict__ bn_b, const float* __restrict__ dw,
        const float* __restrict__ db, float* __restrict__ out,
        float* __restrict__ gstats) {
    __shared__ float ls[8];
    if (threadIdx.x < 8) ls[threadIdx.x] = 0.f;

    int slab = blockIdx.x & 7, inner = blockIdx.x >> 3;  // XCD swizzle
    int vox = slab * 32768 + inner * 256 + threadIdx.x;  // XCD x owns z in [8x,8x+8)
    int h = vox & 63, wy = (vox >> 6) & 63, d = vox >> 12;
    int lane = threadIdx.x & 63;
    const float inv = 1.f / (float)VOX;

    float zo[9], yo[9];
#pragma unroll
    for (int c = 0; c < 18; c++) {
        float m = stats[c] * inv;
        float var = stats[18 + c] * inv - m * m;
        float rs = rsqrtf(var + 1e-5f);
        float t = fast_tanh(bn_g[c] * ((offs[c * VOX + vox] - m) * rs) + bn_b[c]);
        if (c < 9) zo[c] = t; else yo[c - 9] = t;
    }

    // cumsum outward from center (K=9, CENTER=4)
    float za[9], ya[9];
    za[4] = zo[4]; ya[4] = yo[4];
#pragma unroll
    for (int k = 5; k < 9; k++) { za[k] = za[k - 1] + zo[k]; ya[k] = ya[k - 1] + yo[k]; }
#pragma unroll
    for (int k = 3; k >= 0; k--) { za[k] = za[k + 1] + zo[k]; ya[k] = ya[k + 1] + yo[k]; }

    float acc[16];
#pragma unroll
    for (int co = 0; co < 16; co++) acc[co] = db[co];

#pragma unroll
    for (int k = 0; k < 9; k++) {
        int xi = h + k - 4;
        // x is exactly integer: weight 1 for xi in [0,62], exactly 0 otherwise
        if (xi >= 0 && xi <= 62) {
            float z = (float)d + za[k];
            float y = (float)wy + ya[k];
            int iz = (int)floorf(z), iy = (int)floorf(y);
            int z0 = clampi(iz, 0, 63), z1 = clampi(iz + 1, 0, 63);
            int y0 = clampi(iy, 0, 63), y1 = clampi(iy + 1, 0, 63);
            float wz0 = (float)z1 - z, wz1 = z - (float)z0;
            float wy0 = (float)y1 - y, wy1 = y - (float)y0;
            float w00 = wz0 * wy0, w01 = wz0 * wy1, w10 = wz1 * wy0, w11 = wz1 * wy1;

            const float4* p00 = (const float4*)(ft + (((z0 * 64 + y0) * 64 + xi) << 3));
            const float4* p01 = (const float4*)(ft + (((z0 * 64 + y1) * 64 + xi) << 3));
            const float4* p10 = (const float4*)(ft + (((z1 * 64 + y0) * 64 + xi) << 3));
            const float4* p11 = (const float4*)(ft + (((z1 * 64 + y1) * 64 + xi) << 3));
            float4 a00 = p00[0], b00 = p00[1];
            float4 a01 = p01[0], b01 = p01[1];
            float4 a10 = p10[0], b10 = p10[1];
            float4 a11 = p11[0], b11 = p11[1];

            float v[8];
            v[0] = w00 * a00.x + w01 * a01.x + w10 * a10.x + w11 * a11.x;
            v[1] = w00 * a00.y + w01 * a01.y + w10 * a10.y + w11 * a11.y;
            v[2] = w00 * a00.z + w01 * a01.z + w10 * a10.z + w11 * a11.z;
            v[3] = w00 * a00.w + w01 * a01.w + w10 * a10.w + w11 * a11.w;
            v[4] = w00 * b00.x + w01 * b01.x + w10 * b10.x + w11 * b11.x;
            v[5] = w00 * b00.y + w01 * b01.y + w10 * b10.y + w11 * b11.y;
            v[6] = w00 * b00.z + w01 * b01.z + w10 * b10.z + w11 * b11.z;
            v[7] = w00 * b00.w + w01 * b01.w + w10 * b10.w + w11 * b11.w;

#pragma unroll
            for (int ci = 0; ci < 8; ci++) {
#pragma unroll
                for (int co = 0; co < 16; co++)
                    acc[co] = fmaf(v[ci], dw[(co * 8 + ci) * 9 + k], acc[co]);
            }
        }
    }

#pragma unroll
    for (int co = 0; co < 16; co++) out[co * VOX + vox] = acc[co];

    __syncthreads();  // ls zeroed before atomics
#pragma unroll
    for (int g = 0; g < 4; g++) {
        float s = acc[4 * g] + acc[4 * g + 1] + acc[4 * g + 2] + acc[4 * g + 3];
        float q = acc[4 * g] * acc[4 * g] + acc[4 * g + 1] * acc[4 * g + 1]
                + acc[4 * g + 2] * acc[4 * g + 2] + acc[4 * g + 3] * acc[4 * g + 3];
#pragma unroll
        for (int o = 32; o > 0; o >>= 1) {
            s += __shfl_xor(s, o);
            q += __shfl_xor(q, o);
        }
        if (lane == 0) {
            atomicAdd(&ls[g], s);
            atomicAdd(&ls[4 + g], q);
        }
    }
    __syncthreads();
    if (threadIdx.x < 8) atomicAdd(&gstats[threadIdx.x], ls[threadIdx.x]);
}

// ---- apply GroupNorm + ReLU in place on d_out ----
__global__ void k_gn(const float* __restrict__ gstats, const float* __restrict__ gn_g,
                     const float* __restrict__ gn_b, float* __restrict__ out) {
    int idx = blockIdx.x * 256 + threadIdx.x;  // 16*VOX elements
    int c = idx >> 18;
    int g = c >> 2;
    const float invn = 1.f / (4.f * (float)VOX);
    float m = gstats[g] * invn;
    float var = gstats[4 + g] * invn - m * m;
    float rs = rsqrtf(var + 1e-5f);
    float v = (out[idx] - m) * rs * gn_g[c] + gn_b[c];
    out[idx] = v > 0.f ? v : 0.f;
}

extern "C" void kernel_launch(void* const* d_in, const int* in_sizes, int n_in,
                              void* d_out, int out_size, void* d_ws, size_t ws_size,
                              hipStream_t stream) {
    const float* f    = (const float*)d_in[0];
    const float* offw = (const float*)d_in[1];
    const float* offb = (const float*)d_in[2];
    const float* bng  = (const float*)d_in[3];
    const float* bnb  = (const float*)d_in[4];
    const float* dcnw = (const float*)d_in[5];
    const float* dcnb = (const float*)d_in[6];
    const float* gng  = (const float*)d_in[7];
    const float* gnb  = (const float*)d_in[8];
    float* out = (float*)d_out;

    float* ws     = (float*)d_ws;
    float* ft     = ws;               // 8*VOX floats (featT)
    float* offs   = ws + 8 * VOX;     // 18*VOX floats (raw offset conv)
    float* stats  = offs + 18 * VOX;  // 36 bn stats + 8 gn stats
    float* gstats = stats + 36;
    // wT lives in d_out's first 3888 floats: dead until k_main overwrites out.
    float* wT = out;

    hipLaunchKernelGGL(k_setup, dim3(8209), dim3(256), 0, stream, f, ft, stats, offw, wT);
    hipLaunchKernelGGL(k_conv_off, dim3(1024), dim3(256), 0, stream,
                       f, wT, offb, offs, stats);
    hipLaunchKernelGGL(k_main, dim3(1024), dim3(256), 0, stream,
                       ft, offs, stats, bng, bnb, dcnw, dcnb, out, gstats);
    hipLaunchKernelGGL(k_gn, dim3((16 * VOX) / 256), dim3(256), 0, stream,
                       gstats, gng, gnb, out);
}

// Round 7
// 200.283 us; speedup vs baseline: 1.0325x; 1.0325x over previous
//
#include <hip/hip_runtime.h>
#include <math.h>

#define VOX 262144  // 64^3

__device__ __forceinline__ int clampi(int v, int lo, int hi) {
    return v < lo ? lo : (v > hi ? hi : v);
}

__device__ __forceinline__ float fast_tanh(float x) {
    float e = __expf(2.f * x);
    return 1.f - 2.f / (e + 1.f);
}

// ---- tiny setup: weight transpose wT[k][ci][18] + stats zeroing ----
__global__ void k_wt(const float* __restrict__ w, float* __restrict__ wT,
                     float* __restrict__ stats) {
    if (blockIdx.x == 0 && threadIdx.x < 64) stats[threadIdx.x] = 0.f;
    int i = blockIdx.x * 256 + threadIdx.x;  // over 18*8*27 = 3888
    if (i < 3888) {
        int c = i / 216, r = i % 216;
        int ci = r / 27, k = r % 27;
        wT[(k * 8 + ci) * 18 + c] = w[i];
    }
}

// ---- offset conv (3x3x3, 8->18ch) + BN stats + ft store; CHANNEL-split ----
// 2048 blocks x 256: threads 0-127 -> out-ch 0..8, threads 128-255 -> ch 9..17,
// same 128 voxels (identical f loads -> L1 broadcast). x-neighbors via __shfl.
// All 72 loads unconditional (clamped addr + 0/1 mask) -> deep MLP, no branch
// blocks scheduling. Center tap doubles as the feat transpose (ft) producer.
// XCD d-slab swizzle: block b -> slab b%8.
__global__ __launch_bounds__(256, 4) void k_conv_off(
        const float* __restrict__ f, const float* __restrict__ wT,
        const float* __restrict__ b, float* __restrict__ offs,
        float* __restrict__ ft, float* __restrict__ stats) {
    __shared__ float ls[36];
    if (threadIdx.x < 36) ls[threadIdx.x] = 0.f;

    int lv = threadIdx.x & 127;
    int g = __builtin_amdgcn_readfirstlane(threadIdx.x >> 7);  // 0/1, scalar
    int lane = threadIdx.x & 63;
    int slab = blockIdx.x & 7, inner = blockIdx.x >> 3;  // XCD swizzle
    int vox = slab * 32768 + inner * 128 + lv;
    int h = vox & 63, wy = (vox >> 6) & 63, d = vox >> 12;  // h == lane

    float mh0 = h > 0 ? 1.f : 0.f;
    float mh2 = h < 63 ? 1.f : 0.f;
    int sl0 = lane > 0 ? lane - 1 : 0;
    int sl2 = lane < 63 ? lane + 1 : 63;

    const float* wb = wT + 9 * g;  // scalar base -> s_load weights
    const float* bb = b + 9 * g;

    // ---- all 72 loads, unconditional, clamped ----
    float vv[9][8];
    float mk[9];
#pragma unroll
    for (int p = 0; p < 9; p++) {
        int kd = p / 3, kw = p % 3;
        int dd = d + kd - 1, ww = wy + kw - 1;
        bool ok = ((unsigned)dd < 64u) & ((unsigned)ww < 64u);  // wave-uniform
        mk[p] = ok ? 1.f : 0.f;
        const float* fp = f + (clampi(dd, 0, 63) * 64 + clampi(ww, 0, 63)) * 64 + h;
#pragma unroll
        for (int ci = 0; ci < 8; ci++) vv[p][ci] = fp[ci * VOX];
    }

    // center tap (p=4: dd=d, ww=wy, always in-range) produces featT
    if (g == 0) {
#pragma unroll
        for (int ci = 0; ci < 8; ci++) ft[(vox << 3) + ci] = vv[4][ci];
    }

    float acc[9];
#pragma unroll
    for (int c = 0; c < 9; c++) acc[c] = bb[c];

#pragma unroll
    for (int p = 0; p < 9; p++) {
        float m1 = mk[p], m0 = m1 * mh0, m2 = m1 * mh2;
#pragma unroll
        for (int ci = 0; ci < 8; ci++) {
            float vr = vv[p][ci];
            float v0 = __shfl(vr, sl0) * m0;
            float v2 = __shfl(vr, sl2) * m2;
            float v1 = vr * m1;
            const float* wp = wb + ((p * 3) * 8 + ci) * 18;  // kh stride 144
#pragma unroll
            for (int c = 0; c < 9; c++) {
                float a = acc[c];
                a = fmaf(v0, wp[c], a);
                a = fmaf(v1, wp[144 + c], a);
                a = fmaf(v2, wp[288 + c], a);
                acc[c] = a;
            }
        }
    }

#pragma unroll
    for (int c = 0; c < 9; c++) offs[(9 * g + c) * VOX + vox] = acc[c];

    __syncthreads();  // ls zeroed before atomics
#pragma unroll
    for (int c = 0; c < 9; c++) {
        float s = acc[c], q = acc[c] * acc[c];
#pragma unroll
        for (int o = 32; o > 0; o >>= 1) {
            s += __shfl_xor(s, o);
            q += __shfl_xor(q, o);
        }
        if (lane == 0) {
            atomicAdd(&ls[9 * g + c], s);
            atomicAdd(&ls[18 + 9 * g + c], q);
        }
    }
    __syncthreads();
    if (threadIdx.x < 36) atomicAdd(&stats[threadIdx.x], ls[threadIdx.x]);
}

// ---- main: BN+tanh+cumsum + bilinear(z,y) gather + (1,1,9) conv + GN stats.
//      R2 structure (per-tap branch) + XCD z-slab swizzle for L2 locality. ----
__global__ __launch_bounds__(256) void k_main(
        const float* __restrict__ ft, const float* __restrict__ offs,
        const float* __restrict__ stats, const float* __restrict__ bn_g,
        const float* __restrict__ bn_b, const float* __restrict__ dw,
        const float* __restrict__ db, float* __restrict__ out,
        float* __restrict__ gstats) {
    __shared__ float ls[8];
    if (threadIdx.x < 8) ls[threadIdx.x] = 0.f;

    int slab = blockIdx.x & 7, inner = blockIdx.x >> 3;  // XCD swizzle
    int vox = slab * 32768 + inner * 256 + threadIdx.x;  // XCD x owns z in [8x,8x+8)
    int h = vox & 63, wy = (vox >> 6) & 63, d = vox >> 12;
    int lane = threadIdx.x & 63;
    const float inv = 1.f / (float)VOX;

    float zo[9], yo[9];
#pragma unroll
    for (int c = 0; c < 18; c++) {
        float m = stats[c] * inv;
        float var = stats[18 + c] * inv - m * m;
        float rs = rsqrtf(var + 1e-5f);
        float t = fast_tanh(bn_g[c] * ((offs[c * VOX + vox] - m) * rs) + bn_b[c]);
        if (c < 9) zo[c] = t; else yo[c - 9] = t;
    }

    // cumsum outward from center (K=9, CENTER=4)
    float za[9], ya[9];
    za[4] = zo[4]; ya[4] = yo[4];
#pragma unroll
    for (int k = 5; k < 9; k++) { za[k] = za[k - 1] + zo[k]; ya[k] = ya[k - 1] + yo[k]; }
#pragma unroll
    for (int k = 3; k >= 0; k--) { za[k] = za[k + 1] + zo[k]; ya[k] = ya[k + 1] + yo[k]; }

    float acc[16];
#pragma unroll
    for (int co = 0; co < 16; co++) acc[co] = db[co];

#pragma unroll
    for (int k = 0; k < 9; k++) {
        int xi = h + k - 4;
        // x is exactly integer: weight 1 for xi in [0,62], exactly 0 otherwise
        if (xi >= 0 && xi <= 62) {
            float z = (float)d + za[k];
            float y = (float)wy + ya[k];
            int iz = (int)floorf(z), iy = (int)floorf(y);
            int z0 = clampi(iz, 0, 63), z1 = clampi(iz + 1, 0, 63);
            int y0 = clampi(iy, 0, 63), y1 = clampi(iy + 1, 0, 63);
            float wz0 = (float)z1 - z, wz1 = z - (float)z0;
            float wy0 = (float)y1 - y, wy1 = y - (float)y0;
            float w00 = wz0 * wy0, w01 = wz0 * wy1, w10 = wz1 * wy0, w11 = wz1 * wy1;

            const float4* p00 = (const float4*)(ft + (((z0 * 64 + y0) * 64 + xi) << 3));
            const float4* p01 = (const float4*)(ft + (((z0 * 64 + y1) * 64 + xi) << 3));
            const float4* p10 = (const float4*)(ft + (((z1 * 64 + y0) * 64 + xi) << 3));
            const float4* p11 = (const float4*)(ft + (((z1 * 64 + y1) * 64 + xi) << 3));
            float4 a00 = p00[0], b00 = p00[1];
            float4 a01 = p01[0], b01 = p01[1];
            float4 a10 = p10[0], b10 = p10[1];
            float4 a11 = p11[0], b11 = p11[1];

            float v[8];
            v[0] = w00 * a00.x + w01 * a01.x + w10 * a10.x + w11 * a11.x;
            v[1] = w00 * a00.y + w01 * a01.y + w10 * a10.y + w11 * a11.y;
            v[2] = w00 * a00.z + w01 * a01.z + w10 * a10.z + w11 * a11.z;
            v[3] = w00 * a00.w + w01 * a01.w + w10 * a10.w + w11 * a11.w;
            v[4] = w00 * b00.x + w01 * b01.x + w10 * b10.x + w11 * b11.x;
            v[5] = w00 * b00.y + w01 * b01.y + w10 * b10.y + w11 * b11.y;
            v[6] = w00 * b00.z + w01 * b01.z + w10 * b10.z + w11 * b11.z;
            v[7] = w00 * b00.w + w01 * b01.w + w10 * b10.w + w11 * b11.w;

#pragma unroll
            for (int ci = 0; ci < 8; ci++) {
#pragma unroll
                for (int co = 0; co < 16; co++)
                    acc[co] = fmaf(v[ci], dw[(co * 8 + ci) * 9 + k], acc[co]);
            }
        }
    }

#pragma unroll
    for (int co = 0; co < 16; co++) out[co * VOX + vox] = acc[co];

    __syncthreads();  // ls zeroed before atomics
#pragma unroll
    for (int g = 0; g < 4; g++) {
        float s = acc[4 * g] + acc[4 * g + 1] + acc[4 * g + 2] + acc[4 * g + 3];
        float q = acc[4 * g] * acc[4 * g] + acc[4 * g + 1] * acc[4 * g + 1]
                + acc[4 * g + 2] * acc[4 * g + 2] + acc[4 * g + 3] * acc[4 * g + 3];
#pragma unroll
        for (int o = 32; o > 0; o >>= 1) {
            s += __shfl_xor(s, o);
            q += __shfl_xor(q, o);
        }
        if (lane == 0) {
            atomicAdd(&ls[g], s);
            atomicAdd(&ls[4 + g], q);
        }
    }
    __syncthreads();
    if (threadIdx.x < 8) atomicAdd(&gstats[threadIdx.x], ls[threadIdx.x]);
}

// ---- apply GroupNorm + ReLU in place on d_out, float4-vectorized ----
__global__ void k_gn(const float* __restrict__ gstats, const float* __restrict__ gn_g,
                     const float* __restrict__ gn_b, float* __restrict__ out) {
    int i = blockIdx.x * 256 + threadIdx.x;  // over 16*VOX/4 float4s
    int c = i >> 16;                         // (i*4) >> 18
    int g = c >> 2;
    const float invn = 1.f / (4.f * (float)VOX);
    float m = gstats[g] * invn;
    float var = gstats[4 + g] * invn - m * m;
    float rs = rsqrtf(var + 1e-5f) * gn_g[c];
    float bias = gn_b[c];
    float4 v = ((float4*)out)[i];
    v.x = fmaxf((v.x - m) * rs + bias, 0.f);
    v.y = fmaxf((v.y - m) * rs + bias, 0.f);
    v.z = fmaxf((v.z - m) * rs + bias, 0.f);
    v.w = fmaxf((v.w - m) * rs + bias, 0.f);
    ((float4*)out)[i] = v;
}

extern "C" void kernel_launch(void* const* d_in, const int* in_sizes, int n_in,
                              void* d_out, int out_size, void* d_ws, size_t ws_size,
                              hipStream_t stream) {
    const float* f    = (const float*)d_in[0];
    const float* offw = (const float*)d_in[1];
    const float* offb = (const float*)d_in[2];
    const float* bng  = (const float*)d_in[3];
    const float* bnb  = (const float*)d_in[4];
    const float* dcnw = (const float*)d_in[5];
    const float* dcnb = (const float*)d_in[6];
    const float* gng  = (const float*)d_in[7];
    const float* gnb  = (const float*)d_in[8];
    float* out = (float*)d_out;

    float* ws     = (float*)d_ws;
    float* ft     = ws;               // 8*VOX floats (featT, produced by k_conv_off)
    float* offs   = ws + 8 * VOX;     // 18*VOX floats (raw offset conv)
    float* stats  = offs + 18 * VOX;  // 36 bn stats + 8 gn stats
    float* gstats = stats + 36;
    // wT lives in d_out's first 3888 floats: dead until k_main overwrites out.
    float* wT = out;

    hipLaunchKernelGGL(k_wt, dim3(16), dim3(256), 0, stream, offw, wT, stats);
    hipLaunchKernelGGL(k_conv_off, dim3(2048), dim3(256), 0, stream,
                       f, wT, offb, offs, ft, stats);
    hipLaunchKernelGGL(k_main, dim3(1024), dim3(256), 0, stream,
                       ft, offs, stats, bng, bnb, dcnw, dcnb, out, gstats);
    hipLaunchKernelGGL(k_gn, dim3((16 * VOX / 4) / 256), dim3(256), 0, stream,
                       gstats, gng, gnb, out);
}